// Round 4
// baseline (406.842 us; speedup 1.0000x reference)
//
#include <hip/hip_runtime.h>

typedef __bf16 bf16x8 __attribute__((ext_vector_type(8)));
typedef __bf16 bf16x4 __attribute__((ext_vector_type(4)));
typedef float f32x4 __attribute__((ext_vector_type(4)));

#define S_BARRIER() asm volatile("s_barrier" ::: "memory")
#define WAITCNT_VM(n) asm volatile("s_waitcnt vmcnt(" #n ")" ::: "memory")
#define WAITCNT_LGKM0() asm volatile("s_waitcnt lgkmcnt(0)" ::: "memory")

// ---------------------------------------------------------------------------
// Weight prep only (LN is fused into the down-proj GEMM).
// Blocks [0, ntile_d): W_down 32x32 transpose tiles with GAMMA FOLDED IN:
//     Wtd[n][k] = bf16(gamma[k] * W_down[k][n])
//   plus atomically-accumulated correction vectors:
//     C1[n]  += sum_k float(bf16(gamma[k]*W[k][n]))   (cancels the -mu term
//               exactly against the same bf16 weights the GEMM uses)
//     C2b[n] += sum_k beta[k]*W[k][n]                 (C2b pre-seeded b_down)
// Blocks [ntile_d, 2*ntile_d): plain W_up transpose -> bf16 Wtu[d][k].
// ---------------------------------------------------------------------------
__global__ __launch_bounds__(256) void prep_w_kernel(
    const float* __restrict__ Wd, __bf16* __restrict__ Wtd,
    const float* __restrict__ Wu, __bf16* __restrict__ Wtu,
    const float* __restrict__ g, const float* __restrict__ be,
    float* __restrict__ C1, float* __restrict__ C2b,
    int D, int Db) {
    const int ntile_d = (Db / 32) * (D / 32);
    __shared__ float t[32][33];
    const int c = threadIdx.x & 31, r0 = threadIdx.x >> 5;
    if ((int)blockIdx.x < ntile_d) {
        const int K = D, N = Db, tile = blockIdx.x;
        const int tn = tile % (N / 32), tk = tile / (N / 32);
        const int n0 = tn * 32, k0 = tk * 32;
#pragma unroll
        for (int r = r0; r < 32; r += 8)
            t[r][c] = Wd[(size_t)(k0 + r) * N + n0 + c];
        __syncthreads();
        const float gv = g[k0 + c];   // k index of this thread's column is k0+c
        const float bv = be[k0 + c];
        float c1p[4], c2p[4];
#pragma unroll
        for (int u = 0; u < 4; ++u) {
            const int r = r0 + u * 8;              // output n index = n0+r
            const float wv = t[c][r];              // W[k0+c][n0+r]
            const __bf16 w16 = (__bf16)(gv * wv);
            Wtd[(size_t)(n0 + r) * K + k0 + c] = w16;
            c1p[u] = (float)w16;
            c2p[u] = bv * wv;
        }
        // reduce over k-offset c (32 lanes of the half-wave)
#pragma unroll
        for (int o = 16; o > 0; o >>= 1)
#pragma unroll
            for (int u = 0; u < 4; ++u) {
                c1p[u] += __shfl_xor(c1p[u], o);
                c2p[u] += __shfl_xor(c2p[u], o);
            }
        if (c == 0)
#pragma unroll
            for (int u = 0; u < 4; ++u) {
                atomicAdd(&C1[n0 + r0 + u * 8], c1p[u]);
                atomicAdd(&C2b[n0 + r0 + u * 8], c2p[u]);
            }
    } else {
        const int K = Db, N = D, tile = blockIdx.x - ntile_d;
        const int tn = tile % (N / 32), tk = tile / (N / 32);
        const int n0 = tn * 32, k0 = tk * 32;
#pragma unroll
        for (int r = r0; r < 32; r += 8)
            t[r][c] = Wu[(size_t)(k0 + r) * N + n0 + c];
        __syncthreads();
#pragma unroll
        for (int r = r0; r < 32; r += 8)
            Wtu[(size_t)(n0 + r) * K + k0 + c] = (__bf16)t[c][r];
    }
}

// ---------------------------------------------------------------------------
// FUSED LayerNorm + down-proj + SiLU.
// GEMM over RAW fp32 hidden (cast bf16 at stage time) against gamma-folded
// Wtd; LN applied algebraically in the epilogue:
//   z = silu( rstd*acc - (rstd*mu)*C1[n] + C2b[n] )
// Row stats (s, ss) accumulate for free during A staging: each thread stages
// one fixed row (arow = wave*16+lrow) and a fixed k-chunk set
// (chunk=(lane&3)^(lrow&3), bijective over lane&3 => exact coverage), so a
// 2-step shfl_xor over lane bits 0-1 at loop exit yields the full row sums.
// A is reg-staged (fp32 global -> cast -> ds_write, SINGLE LDS buffer:
// written and read inside the same barrier pair); B keeps the proven
// global_load_lds double-buffer. Swizzle: LDS slot (lane&3) holds global
// chunk (lane&3)^(row&3) for both A and B; readers use q^(c&3) as before.
// 64x128 tile, 1024 blocks, ~20.5KB LDS, 4 blocks/CU.
// ---------------------------------------------------------------------------
__global__ __launch_bounds__(256, 4) void fused_ln_down(
    const float* __restrict__ X, const __bf16* __restrict__ Bt,
    const float* __restrict__ C1, const float* __restrict__ C2b,
    __bf16* __restrict__ Z, int M, int N, int K) {
    constexpr int BM = 64, BN = 128, BK = 32;
    constexpr int WM = 32, WN = 64, MI = 2, NJ = 4;
    __shared__ __align__(16) __bf16 Ads[BM * BK];  // single buffer
    __shared__ __align__(16) __bf16 Bds[2][BN * BK];
    __shared__ float sRow[BM], ssRow[BM];

    const int tid = threadIdx.x;
    const int wave = tid >> 6, lane = tid & 63;
    const int bn = blockIdx.x, bm = blockIdx.y;
    const int row0 = bm * BM, col0 = bn * BN;
    const int wr = wave >> 1, wc = wave & 1;

    f32x4 acc[MI][NJ] = {};

    const int lrow = lane >> 2;                    // 0..15
    const int chunk = (lane & 3) ^ (lrow & 3);     // global k-chunk staged
    const int arow = wave * 16 + lrow;             // 0..63: this thread's A row
    const float* Axr = X + (size_t)(row0 + arow) * K + chunk * 8;
    const __bf16* Bg = Bt + (size_t)col0 * K;
    const int lk = chunk * 8;

    const int c = lane & 15, q = lane >> 4;

    auto stageB = [&](int k0, int b) {
#pragma unroll
        for (int p = 0; p < 2; ++p) {
            const int r = wave * 32 + p * 16;  // wave-uniform B group
            __builtin_amdgcn_global_load_lds(
                (__attribute__((address_space(1))) void*)(Bg + (size_t)(r + lrow) * K + k0 + lk),
                (__attribute__((address_space(3))) void*)(&Bds[b][r * BK]),
                16, 0, 0);
        }
    };

    float s = 0.f, ss = 0.f;
    const int nk = K / BK;
    stageB(0, 0);
    float4 a0 = *(const float4*)(Axr);
    float4 a1 = *(const float4*)(Axr + 4);
    for (int it = 0; it < nk; ++it) {
        const int cur = it & 1;
        float4 n0, n1;
        if (it + 1 < nk) {
            stageB((it + 1) * BK, cur ^ 1);
            n0 = *(const float4*)(Axr + (it + 1) * BK);
            n1 = *(const float4*)(Axr + (it + 1) * BK + 4);
            WAITCNT_VM(4);  // 4 newest (next tile) stay in flight; cur done
        } else {
            WAITCNT_VM(0);
        }
        // stats + cast + LDS write of current A chunk (slot = lane&3)
        s += a0.x + a0.y + a0.z + a0.w + a1.x + a1.y + a1.z + a1.w;
        ss += a0.x * a0.x + a0.y * a0.y + a0.z * a0.z + a0.w * a0.w +
              a1.x * a1.x + a1.y * a1.y + a1.z * a1.z + a1.w * a1.w;
        bf16x8 av;
        av[0] = (__bf16)a0.x; av[1] = (__bf16)a0.y;
        av[2] = (__bf16)a0.z; av[3] = (__bf16)a0.w;
        av[4] = (__bf16)a1.x; av[5] = (__bf16)a1.y;
        av[6] = (__bf16)a1.z; av[7] = (__bf16)a1.w;
        *(bf16x8*)(&Ads[arow * BK + (lane & 3) * 8]) = av;
        WAITCNT_LGKM0();  // my ds_write retired
        S_BARRIER();      // all waves: A written, B(cur) DMA landed

        bf16x8 afW[NJ], bfA[MI];
#pragma unroll
        for (int j = 0; j < NJ; ++j) {
            const int rl = wc * WN + j * 16 + c;
            afW[j] = *(const bf16x8*)(&Bds[cur][rl * BK + ((q ^ (c & 3)) * 8)]);
        }
#pragma unroll
        for (int i = 0; i < MI; ++i) {
            const int rl = wr * WM + i * 16 + c;
            bfA[i] = *(const bf16x8*)(&Ads[rl * BK + ((q ^ (c & 3)) * 8)]);
        }
#pragma unroll
        for (int i = 0; i < MI; ++i)
#pragma unroll
            for (int j = 0; j < NJ; ++j)
                acc[i][j] = __builtin_amdgcn_mfma_f32_16x16x32_bf16(afW[j], bfA[i],
                                                                    acc[i][j], 0, 0, 0);
        WAITCNT_LGKM0();  // my LDS reads retired
        S_BARRIER();      // buffers safe to overwrite next iteration
        a0 = n0; a1 = n1;
    }

    // finalize row stats: reduce over lane bits 0-1 (the 4 chunk-lanes)
    s += __shfl_xor(s, 1);  s += __shfl_xor(s, 2);
    ss += __shfl_xor(ss, 1); ss += __shfl_xor(ss, 2);
    if ((lane & 3) == 0) { sRow[arow] = s; ssRow[arow] = ss; }
    __syncthreads();

    const float rK = 1.f / (float)K;
    // Epilogue (swapped-D layout): lane holds z[rowg][colb + 0..3]
#pragma unroll
    for (int i = 0; i < MI; ++i) {
        const int rl = wr * WM + i * 16 + c;
        const float mu = sRow[rl] * rK;
        const float var = ssRow[rl] * rK - mu * mu;
        const float rstd = rsqrtf(var + 1e-5f);
        const float mrs = mu * rstd;
        const int rowg = row0 + rl;
#pragma unroll
        for (int j = 0; j < NJ; ++j) {
            const int colb = col0 + wc * WN + j * 16 + q * 4;
            const float4 c1 = *(const float4*)(C1 + colb);
            const float4 c2 = *(const float4*)(C2b + colb);
            float v0 = rstd * acc[i][j][0] - mrs * c1.x + c2.x;
            float v1 = rstd * acc[i][j][1] - mrs * c1.y + c2.y;
            float v2 = rstd * acc[i][j][2] - mrs * c1.z + c2.z;
            float v3 = rstd * acc[i][j][3] - mrs * c1.w + c2.w;
            bf16x4 o;
            o[0] = (__bf16)(v0 / (1.f + __expf(-v0)));
            o[1] = (__bf16)(v1 / (1.f + __expf(-v1)));
            o[2] = (__bf16)(v2 / (1.f + __expf(-v2)));
            o[3] = (__bf16)(v3 / (1.f + __expf(-v3)));
            *(bf16x4*)(Z + (size_t)rowg * N + colb) = o;
        }
    }
}

// ---------------------------------------------------------------------------
// Up-proj GEMM (unchanged, proven): BMxBN, BK=32, dbuf LDS, global_load_lds,
// XOR chunk swizzle, operand-swap MFMA, residual fp32 epilogue with hoisted
// hid loads.
// ---------------------------------------------------------------------------
template <int EPI, int BM, int BN, int MINW>
__global__ __launch_bounds__(256, MINW) void gemm_bt(
    const __bf16* __restrict__ A, const __bf16* __restrict__ Bt,
    const float* __restrict__ bias, const float* __restrict__ hid,
    const float* __restrict__ alpha_p, void* __restrict__ Cout,
    int M, int N, int K) {
    constexpr int BK = 32;
    constexpr int WM = BM / 2, WN = BN / 2;
    constexpr int MI = WM / 16, NJ = WN / 16;
    constexpr int GA = BM / 64, GB = BN / 64;
    constexpr int L = GA + GB;
    __shared__ __align__(16) __bf16 Ads[2][BM * BK];
    __shared__ __align__(16) __bf16 Bds[2][BN * BK];

    const int tid = threadIdx.x;
    const int wave = tid >> 6;
    const int lane = tid & 63;
    const int bn = blockIdx.x, bm = blockIdx.y;
    const int row0 = bm * BM, col0 = bn * BN;
    const int wr = wave >> 1, wc = wave & 1;

    f32x4 acc[MI][NJ] = {};

    const __bf16* Ag = A + (size_t)row0 * K;
    const __bf16* Bg = Bt + (size_t)col0 * K;
    const int lrow = lane >> 2;
    const int lk = ((lane & 3) ^ (lrow & 3)) * 8;

    const int c = lane & 15;
    const int q = lane >> 4;

    auto stage = [&](int k0, int b) {
#pragma unroll
        for (int p = 0; p < GA; ++p) {
            const int r = wave * (16 * GA) + p * 16;
            __builtin_amdgcn_global_load_lds(
                (__attribute__((address_space(1))) void*)(Ag + (size_t)(r + lrow) * K + k0 + lk),
                (__attribute__((address_space(3))) void*)(&Ads[b][r * BK]),
                16, 0, 0);
        }
#pragma unroll
        for (int p = 0; p < GB; ++p) {
            const int r = wave * (16 * GB) + p * 16;
            __builtin_amdgcn_global_load_lds(
                (__attribute__((address_space(1))) void*)(Bg + (size_t)(r + lrow) * K + k0 + lk),
                (__attribute__((address_space(3))) void*)(&Bds[b][r * BK]),
                16, 0, 0);
        }
    };

    const int nk = K / BK;
    stage(0, 0);
    for (int it = 0; it < nk; ++it) {
        const int cur = it & 1;
        if (it + 1 < nk) {
            stage((it + 1) * BK, cur ^ 1);
            if constexpr (L == 3) WAITCNT_VM(3); else WAITCNT_VM(4);
        } else {
            WAITCNT_VM(0);
        }
        S_BARRIER();

        bf16x8 afW[NJ], bfA[MI];
#pragma unroll
        for (int j = 0; j < NJ; ++j) {
            const int rl = wc * WN + j * 16 + c;
            afW[j] = *(const bf16x8*)(&Bds[cur][rl * BK + ((q ^ (c & 3)) * 8)]);
        }
#pragma unroll
        for (int i = 0; i < MI; ++i) {
            const int rl = wr * WM + i * 16 + c;
            bfA[i] = *(const bf16x8*)(&Ads[cur][rl * BK + ((q ^ (c & 3)) * 8)]);
        }
#pragma unroll
        for (int i = 0; i < MI; ++i)
#pragma unroll
            for (int j = 0; j < NJ; ++j)
                acc[i][j] = __builtin_amdgcn_mfma_f32_16x16x32_bf16(afW[j], bfA[i],
                                                                    acc[i][j], 0, 0, 0);
        WAITCNT_LGKM0();
        S_BARRIER();
    }

    float alpha = (EPI == 1) ? *alpha_p : 0.f;
#pragma unroll
    for (int i = 0; i < MI; ++i) {
        const int rowg = row0 + wr * WM + i * 16 + c;
        if (EPI == 0) {
#pragma unroll
            for (int j = 0; j < NJ; ++j) {
                const int colb = col0 + wc * WN + j * 16 + q * 4;
                const float4 bv = *(const float4*)(bias + colb);
                float v0 = acc[i][j][0] + bv.x;
                float v1 = acc[i][j][1] + bv.y;
                float v2 = acc[i][j][2] + bv.z;
                float v3 = acc[i][j][3] + bv.w;
                const size_t idx = (size_t)rowg * N + colb;
                bf16x4 o;
                o[0] = (__bf16)(v0 / (1.f + __expf(-v0)));
                o[1] = (__bf16)(v1 / (1.f + __expf(-v1)));
                o[2] = (__bf16)(v2 / (1.f + __expf(-v2)));
                o[3] = (__bf16)(v3 / (1.f + __expf(-v3)));
                *(bf16x4*)((__bf16*)Cout + idx) = o;
            }
        } else {
            float4 hv[NJ];
#pragma unroll
            for (int j = 0; j < NJ; ++j) {
                const int colb = col0 + wc * WN + j * 16 + q * 4;
                hv[j] = *(const float4*)(hid + (size_t)rowg * N + colb);
            }
#pragma unroll
            for (int j = 0; j < NJ; ++j) {
                const int colb = col0 + wc * WN + j * 16 + q * 4;
                const float4 bv = *(const float4*)(bias + colb);
                float v0 = acc[i][j][0] + bv.x;
                float v1 = acc[i][j][1] + bv.y;
                float v2 = acc[i][j][2] + bv.z;
                float v3 = acc[i][j][3] + bv.w;
                float4 o;
                o.x = hv[j].x + alpha * (v0 - hv[j].x);
                o.y = hv[j].y + alpha * (v1 - hv[j].y);
                o.z = hv[j].z + alpha * (v2 - hv[j].z);
                o.w = hv[j].w + alpha * (v3 - hv[j].w);
                *(float4*)((float*)Cout + (size_t)rowg * N + colb) = o;
            }
        }
    }
}

// ---------------------------------------------------------------------------
// Launch
// ---------------------------------------------------------------------------
extern "C" void kernel_launch(void* const* d_in, const int* in_sizes, int n_in,
                              void* d_out, int out_size, void* d_ws, size_t ws_size,
                              hipStream_t stream) {
    const float* hidden = (const float*)d_in[0];
    const float* ln_gamma = (const float*)d_in[1];
    const float* ln_beta = (const float*)d_in[2];
    const float* W_down = (const float*)d_in[3];
    const float* b_down = (const float*)d_in[4];
    const float* W_up = (const float*)d_in[5];
    const float* b_up = (const float*)d_in[6];
    const float* alpha = (const float*)d_in[7];
    float* out = (float*)d_out;

    const int D = in_sizes[2];      // 2048
    const int Db = in_sizes[4];     // 512
    const int M = in_sizes[0] / D;  // 16384

    char* w = (char*)d_ws;
    __bf16* z = (__bf16*)w;   w += (size_t)M * Db * sizeof(__bf16);
    __bf16* Wtd = (__bf16*)w; w += (size_t)D * Db * sizeof(__bf16);  // [Db][D]
    __bf16* Wtu = (__bf16*)w; w += (size_t)Db * D * sizeof(__bf16);  // [D][Db]
    float* C1 = (float*)w;    w += Db * sizeof(float);
    float* C2b = (float*)w;   w += Db * sizeof(float);

    hipMemsetAsync(C1, 0, Db * sizeof(float), stream);
    hipMemcpyAsync(C2b, b_down, Db * sizeof(float), hipMemcpyDeviceToDevice, stream);

    const int ntiles = 2 * (D / 32) * (Db / 32);
    prep_w_kernel<<<ntiles, 256, 0, stream>>>(W_down, Wtd, W_up, Wtu,
                                              ln_gamma, ln_beta, C1, C2b, D, Db);

    // fused LN + down-proj + SiLU: raw fp32 hidden in, bf16 z out.
    fused_ln_down<<<dim3(Db / 128, M / 64), 256, 0, stream>>>(
        hidden, Wtd, C1, C2b, z, M, Db, D);

    // up-proj: unchanged proven kernel.
    gemm_bt<1, 128, 128, 4><<<dim3(D / 128, M / 128), 256, 0, stream>>>(
        z, Wtu, b_up, hidden, alpha, (void*)out, M, D, Db);
}